// Round 5
// baseline (1126.311 us; speedup 1.0000x reference)
//
#include <hip/hip_runtime.h>
#include <hip/hip_fp16.h>

typedef _Float16 f16;
typedef _Float16 f16x8 __attribute__((ext_vector_type(8)));
typedef float f32x4 __attribute__((ext_vector_type(4)));
typedef int int4v __attribute__((ext_vector_type(4)));
typedef unsigned char uchar;

#define BM 256
#define BN 256
// K_STEP = 64; LDS: A 2x32KB at 0, B 2x32KB at 65536.

typedef const __attribute__((address_space(1))) unsigned int* gas_ptr;
typedef __attribute__((address_space(3))) unsigned int* las_ptr;

__device__ __forceinline__ void gload_lds16(const void* g, void* l) {
    __builtin_amdgcn_global_load_lds((gas_ptr)g, (las_ptr)l, 16, 0, 0);
}

// ---------------------------------------------------------------------------
// Pre-pass 1: xs[M,K] = fp16(x / smooth)
// ---------------------------------------------------------------------------
__global__ __launch_bounds__(256) void smooth_kernel(
    const float* __restrict__ x, const float* __restrict__ smooth,
    f16* __restrict__ xs, int MK, int K)
{
    const int t = blockIdx.x * 256 + threadIdx.x;
    const int i0 = t * 8;
    if (i0 >= MK) return;
    const int k0 = i0 % K;
    const f32x4 a0 = *(const f32x4*)(x + i0);
    const f32x4 a1 = *(const f32x4*)(x + i0 + 4);
    const f32x4 s0 = *(const f32x4*)(smooth + k0);
    const f32x4 s1 = *(const f32x4*)(smooth + k0 + 4);
    f16x8 o;
#pragma unroll
    for (int j = 0; j < 4; ++j) {
        o[j]     = (f16)(a0[j] / s0[j]);
        o[j + 4] = (f16)(a1[j] / s1[j]);
    }
    *(f16x8*)(xs + i0) = o;
}

// ---------------------------------------------------------------------------
// Pre-pass 2: repack int32-per-byte -> true packed nibbles (4x smaller).
// out[e] = (uchar)(packed[e] & 255); 16 bytes per thread.
// ---------------------------------------------------------------------------
__global__ __launch_bounds__(256) void repack_kernel(
    const int* __restrict__ packed, uchar* __restrict__ bpk, int total16)
{
    const int i = blockIdx.x * 256 + threadIdx.x;
    if (i >= total16) return;
    const int base = i * 16;
    int4v o;
#pragma unroll
    for (int w = 0; w < 4; ++w) {
        const int4v p = *(const int4v*)(packed + base + w * 4);
        o[w] = (p[0] & 255) | ((p[1] & 255) << 8) | ((p[2] & 255) << 16) | ((p[3] & 255) << 24);
    }
    *(int4v*)(bpk + base) = o;
}

// ---------------------------------------------------------------------------
// Unpack 2 chunks (8 bytes -> 16 f16) of a packed 16B slice into swizzled LDS.
// ---------------------------------------------------------------------------
__device__ __forceinline__ void unpack2(const int4v pk, int c0, float scf, float zpf,
                                        char* bb, int rB, int hB)
{
#pragma unroll
    for (int c = 0; c < 2; ++c) {
        const int cj = c0 + c;
        const int d = pk[cj];
        f16x8 o;
#pragma unroll
        for (int b = 0; b < 4; ++b) {
            const int by = (d >> (8 * b)) & 255;
            const float lo = (float)((by & 15) - 8);
            const float hi = (float)((by >> 4) - 8);
            o[2 * b]     = (f16)((lo - zpf) * scf);
            o[2 * b + 1] = (f16)((hi - zpf) * scf);
        }
        *(f16x8*)(bb + (((hB * 4 + cj) ^ (rB & 7)) << 4)) = o;
    }
}

// ---------------------------------------------------------------------------
// GEMM: C = xs * W^T + bias; W dequantized in-kernel from true-packed int4.
// 256x256 tile, K_STEP=64, 4 phases/step, 8 waves (2x4), XOR-chunk-swizzled
// LDS (verified conflict-free), supertile XCD swizzle with 2bm x 16bn chunks
// (A panels L2-resident). B staged as packed bytes (8KB/step) -> unpacked to
// f16 LDS of the NEXT buffer during ph3/ph4 (race-free), lgkmcnt(0) before
// the boundary barrier for ds_write visibility.
// ---------------------------------------------------------------------------
__global__ __launch_bounds__(512, 2) void gemm_kernel(
    const f16* __restrict__ As,        // [M, K]
    const uchar* __restrict__ Bpk,     // [N, K/2] true-packed
    const float* __restrict__ wscale,  // [G, N]
    const float* __restrict__ wzero,   // [G, N]
    const float* __restrict__ bias,    // [N]
    float* __restrict__ C,             // [M, N]
    int M, int N, int K)
{
    __shared__ char lds[131072];

    const int t = threadIdx.x;
    const int lane = t & 63;
    const int wid = t >> 6;
    const int wr = wid >> 2;          // 0..1
    const int wc = wid & 3;           // 0..3
    const int fr = lane & 15;
    const int fq = lane >> 4;

    const int nbm = M / BM;           // 32
    const int nbn = N / BN;           // 43
    const int nwg = nbm * nbn;        // 1376
    const int bid = (int)blockIdx.x;

    int bm, bn;
    if (nbm == 32 && nbn == 43) {
        // supertiles 16x16 blocks; per-XCD rounds of 32 blocks = 2bm x 16bn
        const int x = bid & 7, s = bid >> 3;        // s in 0..171
        const int r = s >> 5, q = s & 31;
        const int pos = (r < 5) ? (r * 256 + x * 32 + q)
                                : (1280 + x * 12 + (s - 160));
        int st, w;
        if (pos < 1024)      { st = pos >> 8; w = pos & 255; }
        else if (pos < 1200) { st = 4;        w = pos - 1024; }
        else                 { st = 5;        w = pos - 1200; }
        if (st < 4) { bm = (st & 1) * 16 + (w >> 4); bn = (st >> 1) * 16 + (w & 15); }
        else        { bm = (st & 1) * 16 + (w / 11); bn = 32 + (w % 11); }
    } else {
        const int cpx = nwg >> 3;
        const int wg = (bid & 7) * cpx + (bid >> 3);
        bm = wg % nbm; bn = wg / nbm;
    }
    const size_t m0 = (size_t)bm * BM;
    const size_t n0 = (size_t)bn * BN;

    // ---- A staging geometry (gload_lds, XOR-swizzled global source) ----
    const int rowA = t >> 3;                            // 0..63
    const int sck8 = (((t & 7) ^ ((t >> 3) & 7)) << 3); // f16 units
    const f16* gAs = As + (m0 + rowA) * (size_t)K + sck8;

#define STAGE_A(h, Tst) do { char* _d = lds + (((Tst)&1) << 15) + ((h) << 14) + t*16; \
    gload_lds16(gAs + (size_t)((h)*128) * K + (size_t)(Tst)*64, _d); \
    gload_lds16(gAs + (size_t)((h)*128 + 64) * K + (size_t)(Tst)*64, _d + 8192); } while (0)

    // ---- B packed-staging geometry ----
    const int rB = t >> 1;            // tile row 0..255
    const int hB = t & 1;             // k-half (chunks hB*4..hB*4+3)
    const uchar* gPk = Bpk + (size_t)(n0 + rB) * (K >> 1) + hB * 16;

    // ---- ds_read lane constants ----
    const int r7 = fr & 7;
    const int coff0 = ((fq ^ r7) << 4);
    const int coff1 = (((fq ^ r7) ^ 4) << 4);
    const int aBase = (wr << 14) + fr * 128;
    const int bBase = 65536 + ((wc >> 1) << 14) + ((wc & 1) << 13) + fr * 128;

#define LDA(db, m, kk) (*(const f16x8*)(lds + (db) + aBase + (m)*2048 + ((kk) ? coff1 : coff0)))
#define LDB(db, n, kk) (*(const f16x8*)(lds + (db) + bBase + (n)*2048 + ((kk) ? coff1 : coff0)))

    f32x4 acc[8][4];
#pragma unroll
    for (int m = 0; m < 8; ++m)
#pragma unroll
        for (int n = 0; n < 4; ++n)
            acc[m][n] = {0.f, 0.f, 0.f, 0.f};

    const int NT = K >> 6;            // 64

    // ---- prologue: A(0), A(1) staged; B(0) loaded+unpacked into buf0 ----
    STAGE_A(0, 0); STAGE_A(1, 0); STAGE_A(0, 1); STAGE_A(1, 1);
    {
        const int4v pk0 = *(const int4v*)(gPk);
        const float sc0 = wscale[n0 + rB];
        const float zp0 = wzero[n0 + rB];
        asm volatile("s_waitcnt vmcnt(0)" ::: "memory");
        char* bb = lds + 65536 + rB * 128;
        unpack2(pk0, 0, sc0, zp0, bb, rB, hB);
        unpack2(pk0, 2, sc0, zp0, bb, rB, hB);
    }
    asm volatile("s_waitcnt lgkmcnt(0)" ::: "memory");
    __builtin_amdgcn_s_barrier();

#pragma unroll 1
    for (int T = 0; T < NT; ++T) {
        const int db = (T & 1) << 15;
        const bool hasB = (T + 1) < NT;
        const bool hasA2 = (T + 2) < NT;
        f16x8 a03[8], a47[8], b01[4], b23[4];
        int4v pkn;
        float scn = 0.f, zpn = 0.f;

        // ===== ph1: read a03,b01; issue Bpk(T+1)+scales; MFMA m0-3 x n0-1 =====
#pragma unroll
        for (int m = 0; m < 4; ++m) { a03[2*m] = LDA(db, m, 0); a03[2*m+1] = LDA(db, m, 1); }
#pragma unroll
        for (int n = 0; n < 2; ++n) { b01[2*n] = LDB(db, n, 0); b01[2*n+1] = LDB(db, n, 1); }
        if (hasB) {
            const int g1 = (T + 1) >> 1;
            pkn = *(const int4v*)(gPk + (size_t)(T + 1) * 32);
            scn = wscale[(size_t)g1 * N + n0 + rB];
            zpn = wzero[(size_t)g1 * N + n0 + rB];
        }
        __builtin_amdgcn_s_barrier();
        __builtin_amdgcn_s_setprio(1);
#pragma unroll
        for (int m = 0; m < 4; ++m)
#pragma unroll
            for (int n = 0; n < 2; ++n) {
                acc[m][n] = __builtin_amdgcn_mfma_f32_16x16x32_f16(a03[2*m],   b01[2*n],   acc[m][n], 0, 0, 0);
                acc[m][n] = __builtin_amdgcn_mfma_f32_16x16x32_f16(a03[2*m+1], b01[2*n+1], acc[m][n], 0, 0, 0);
            }
        __builtin_amdgcn_s_setprio(0);
        __builtin_amdgcn_s_barrier();

        // ===== ph2: read a47; MFMA m4-7 x n0-1 =====
#pragma unroll
        for (int m = 0; m < 4; ++m) { a47[2*m] = LDA(db, 4 + m, 0); a47[2*m+1] = LDA(db, 4 + m, 1); }
        __builtin_amdgcn_s_barrier();
        __builtin_amdgcn_s_setprio(1);
#pragma unroll
        for (int m = 0; m < 4; ++m)
#pragma unroll
            for (int n = 0; n < 2; ++n) {
                acc[4+m][n] = __builtin_amdgcn_mfma_f32_16x16x32_f16(a47[2*m],   b01[2*n],   acc[4+m][n], 0, 0, 0);
                acc[4+m][n] = __builtin_amdgcn_mfma_f32_16x16x32_f16(a47[2*m+1], b01[2*n+1], acc[4+m][n], 0, 0, 0);
            }
        __builtin_amdgcn_s_setprio(0);
        __builtin_amdgcn_s_barrier();

        // ===== ph3: read b23; vmcnt(0) (aged loads only); unpack half1 of
        //           B(T+1) into other buf; stage A0(T+2); MFMA m0-3 x n2-3 =====
#pragma unroll
        for (int n = 0; n < 2; ++n) { b23[2*n] = LDB(db, 2 + n, 0); b23[2*n+1] = LDB(db, 2 + n, 1); }
        asm volatile("s_waitcnt vmcnt(0)" ::: "memory");
        if (hasB) {
            char* bb = lds + 65536 + (((T + 1) & 1) << 15) + rB * 128;
            unpack2(pkn, 0, scn, zpn, bb, rB, hB);
        }
        if (hasA2) STAGE_A(0, T + 2);
        __builtin_amdgcn_s_barrier();
        __builtin_amdgcn_s_setprio(1);
#pragma unroll
        for (int m = 0; m < 4; ++m)
#pragma unroll
            for (int n = 0; n < 2; ++n) {
                acc[m][2+n] = __builtin_amdgcn_mfma_f32_16x16x32_f16(a03[2*m],   b23[2*n],   acc[m][2+n], 0, 0, 0);
                acc[m][2+n] = __builtin_amdgcn_mfma_f32_16x16x32_f16(a03[2*m+1], b23[2*n+1], acc[m][2+n], 0, 0, 0);
            }
        __builtin_amdgcn_s_setprio(0);
        __builtin_amdgcn_s_barrier();

        // ===== ph4: unpack half2; stage A1(T+2); MFMA m4-7 x n2-3;
        //           drain LDS writes before boundary barrier =====
        if (hasB) {
            char* bb = lds + 65536 + (((T + 1) & 1) << 15) + rB * 128;
            unpack2(pkn, 2, scn, zpn, bb, rB, hB);
        }
        if (hasA2) STAGE_A(1, T + 2);
        __builtin_amdgcn_s_barrier();
        __builtin_amdgcn_s_setprio(1);
#pragma unroll
        for (int m = 0; m < 4; ++m)
#pragma unroll
            for (int n = 0; n < 2; ++n) {
                acc[4+m][2+n] = __builtin_amdgcn_mfma_f32_16x16x32_f16(a47[2*m],   b23[2*n],   acc[4+m][2+n], 0, 0, 0);
                acc[4+m][2+n] = __builtin_amdgcn_mfma_f32_16x16x32_f16(a47[2*m+1], b23[2*n+1], acc[4+m][2+n], 0, 0, 0);
            }
        __builtin_amdgcn_s_setprio(0);
        asm volatile("s_waitcnt lgkmcnt(0)" ::: "memory");
        __builtin_amdgcn_s_barrier();
    }

    // ---- epilogue: LDS transpose -> coalesced f32x4 stores (+bias) ----
    float* eLds = (float*)lds;                 // [64][260] f32 per pass
    const f32x4 bv = *(const f32x4*)(bias + n0 + lane * 4);
#pragma unroll 1
    for (int p = 0; p < 4; ++p) {
        if (wr == (p >> 1)) {
            const int amb = (p & 1) * 4;
#pragma unroll
            for (int mm = 0; mm < 4; ++mm)
#pragma unroll
                for (int n = 0; n < 4; ++n) {
                    const f32x4 v = acc[amb + mm][n];
                    const int col = wc * 64 + n * 16 + fr;
#pragma unroll
                    for (int r = 0; r < 4; ++r)
                        eLds[(mm * 16 + fq * 4 + r) * 260 + col] = v[r];
                }
        }
        __builtin_amdgcn_s_barrier();
        const size_t growb = m0 + p * 64;
#pragma unroll
        for (int s = 0; s < 8; ++s) {
            const int row = s * 8 + wid;
            f32x4 v = *(const f32x4*)(eLds + row * 260 + lane * 4);
            v += bv;
            *(f32x4*)(&C[(growb + row) * (size_t)N + n0 + lane * 4]) = v;
        }
        __builtin_amdgcn_s_barrier();
    }
}

extern "C" void kernel_launch(void* const* d_in, const int* in_sizes, int n_in,
                              void* d_out, int out_size, void* d_ws, size_t ws_size,
                              hipStream_t stream) {
    const float* x      = (const float*)d_in[0];
    const int* packed   = (const int*)d_in[1];
    const float* wscale = (const float*)d_in[2];
    const float* wzero  = (const float*)d_in[3];
    const float* smooth = (const float*)d_in[4];
    const float* bias   = (const float*)d_in[5];
    float* out = (float*)d_out;

    const int K = in_sizes[4];             // 4096
    const int N = in_sizes[5];             // 11008
    const int M = in_sizes[0] / K;         // 8192
    const int MK = M * K;

    f16* xs = (f16*)d_ws;
    uchar* bpk = (uchar*)d_ws + (size_t)MK * sizeof(f16);

    smooth_kernel<<<(MK / 8 + 255) / 256, 256, 0, stream>>>(x, smooth, xs, MK, K);
    const int total16 = (N * (K >> 1)) / 16;
    repack_kernel<<<(total16 + 255) / 256, 256, 0, stream>>>(packed, bpk, total16);

    const int grid_gemm = (M / BM) * (N / BN);
    gemm_kernel<<<grid_gemm, 512, 0, stream>>>(xs, bpk, wscale, wzero, bias, out, M, N, K);
}

// Round 6
// 1104.146 us; speedup vs baseline: 1.0201x; 1.0201x over previous
//
#include <hip/hip_runtime.h>
#include <hip/hip_fp16.h>

typedef _Float16 f16;
typedef _Float16 f16x8 __attribute__((ext_vector_type(8)));
typedef float f32x4 __attribute__((ext_vector_type(4)));
typedef int int4v __attribute__((ext_vector_type(4)));

#define BM 256
#define BN 128
#define BK 32
#define BUFSZ 24576              // A 16KB + B 8KB
#define NBUF 3

typedef const __attribute__((address_space(1))) unsigned int* gas_ptr;
typedef __attribute__((address_space(3))) unsigned int* las_ptr;

__device__ __forceinline__ void gload_lds16(const void* g, void* l) {
    __builtin_amdgcn_global_load_lds((gas_ptr)g, (las_ptr)l, 16, 0, 0);
}

// ---------------------------------------------------------------------------
// Pre-pass 1: xs[M,K] = fp16(x / smooth)
// ---------------------------------------------------------------------------
__global__ __launch_bounds__(256) void smooth_kernel(
    const float* __restrict__ x, const float* __restrict__ smooth,
    f16* __restrict__ xs, int MK, int K)
{
    const int t = blockIdx.x * 256 + threadIdx.x;
    const int i0 = t * 8;
    if (i0 >= MK) return;
    const int k0 = i0 % K;
    const f32x4 a0 = *(const f32x4*)(x + i0);
    const f32x4 a1 = *(const f32x4*)(x + i0 + 4);
    const f32x4 s0 = *(const f32x4*)(smooth + k0);
    const f32x4 s1 = *(const f32x4*)(smooth + k0 + 4);
    f16x8 o;
#pragma unroll
    for (int j = 0; j < 4; ++j) {
        o[j]     = (f16)(a0[j] / s0[j]);
        o[j + 4] = (f16)(a1[j] / s1[j]);
    }
    *(f16x8*)(xs + i0) = o;
}

// ---------------------------------------------------------------------------
// Pre-pass 2: Bt[N,K] = fp16((q - zp) * scale)
// ---------------------------------------------------------------------------
__global__ __launch_bounds__(256) void dequant_kernel(
    const int* __restrict__ packed,    // [N, K/2]
    const float* __restrict__ wscale,  // [G, N]
    const float* __restrict__ wzero,   // [G, N]
    f16* __restrict__ Bt,              // [N, K]
    int N, int K)
{
    const int perrow = K >> 3;
    const int t = blockIdx.x * 256 + threadIdx.x;
    const int n = t / perrow;
    const int jt = t - n * perrow;
    if (n >= N) return;
    const int k0 = jt << 3;
    const int g = k0 >> 7;
    const int4v p = *(const int4v*)(packed + (size_t)n * (K >> 1) + (jt << 2));
    const float sc = wscale[(size_t)g * N + n];
    const float zp = wzero[(size_t)g * N + n];
    f16x8 o;
#pragma unroll
    for (int b = 0; b < 4; ++b) {
        const int byte = p[b];
        o[2 * b]     = (f16)(((float)((byte & 15) - 8) - zp) * sc);
        o[2 * b + 1] = (f16)(((float)(((byte >> 4) & 15) - 8) - zp) * sc);
    }
    *(f16x8*)(Bt + (size_t)n * K + k0) = o;
}

// ---------------------------------------------------------------------------
// GEMM: C = xs * Bt^T + bias, f32 out.
// 256x128 tile, BK=32, 3-buffer depth-2 pipeline with counted vmcnt(6),
// 4 waves (2x2, 128x64 each), 2 blocks/CU (72KB LDS, launch_bounds(256,2)).
// LDS line = 128B holding 2 rows x 4 chunks; chunkpos c holds content chunk
// c^(line&7) (round-3-verified: 0 bank conflicts). gload_lds dests linear,
// global source inverse-swizzled, ds_read applies the XOR.
// ---------------------------------------------------------------------------
__global__ __launch_bounds__(256, 2) void gemm_kernel(
    const f16* __restrict__ As,       // [M, K]
    const f16* __restrict__ Bt,       // [N, K]
    const float* __restrict__ bias,   // [N]
    float* __restrict__ C,            // [M, N]
    int M, int N, int K)
{
    __shared__ char lds[NBUF * BUFSZ];   // 72 KiB

    const int t = threadIdx.x;
    const int lane = t & 63;
    const int wid = t >> 6;
    const int wr = wid >> 1;          // 0..1 (M)
    const int wc = wid & 1;           // 0..1 (N)
    const int fr = lane & 15;
    const int fq = lane >> 4;         // 0..3

    const int nbm = M / BM;           // 32
    const int nbn = N / BN;           // 86
    const int nwg = nbm * nbn;        // 2752
    const int bid = (int)blockIdx.x;
    const int cpx = nwg >> 3;
    const int wg = ((nwg & 7) == 0) ? ((bid & 7) * cpx + (bid >> 3)) : bid;
    const int bm = wg % nbm;          // bm-major: column blocks share B panel
    const int bn = wg / nbm;
    const size_t m0 = (size_t)bm * BM;
    const size_t n0 = (size_t)bn * BN;

    // ---- staging geometry (256 threads; 4KB per gload round) ----
    // dest (linear): line = g*32 + (t>>3), chunkpos = t&7
    // content chunk sc = (t&7) ^ ((t>>3)&7); row = g*64 + 2*(t>>3) + (sc>>2)
    const int scv = (t & 7) ^ ((t >> 3) & 7);
    const int rbase = 2 * (t >> 3) + (scv >> 2);       // 0..63
    const int kArow = (scv & 3) * 8;
    const f16* gA = As + (m0 + rbase) * (size_t)K + kArow;
    const f16* gB = Bt + (n0 + rbase) * (size_t)K + kArow;

#define STAGE_A(bo, Tst, g) gload_lds16(gA + (size_t)(g) * 64 * K + (size_t)(Tst) * BK, \
                                        lds + (bo) + (g) * 4096 + t * 16)
#define STAGE_B(bo, Tst, g) gload_lds16(gB + (size_t)(g) * 64 * K + (size_t)(Tst) * BK, \
                                        lds + (bo) + 16384 + (g) * 4096 + t * 16)

    // ---- ds_read lane constants (round-3-verified swizzle) ----
    const int aswz16 = ((((fr & 1) << 2) | fq) ^ ((fr >> 1) & 7)) << 4;
    const int aoff = wr * 8192 + ((fr >> 1) << 7) + aswz16;
    const int boff = 16384 + wc * 4096 + ((fr >> 1) << 7) + aswz16;

#define LDA(bo, m) (*(const f16x8*)(lds + (bo) + aoff + (m) * 1024))
#define LDB(bo, n) (*(const f16x8*)(lds + (bo) + boff + (n) * 1024))

    f32x4 acc[8][4];
#pragma unroll
    for (int m = 0; m < 8; ++m)
#pragma unroll
        for (int n = 0; n < 4; ++n)
            acc[m][n] = {0.f, 0.f, 0.f, 0.f};

    const int NT = K >> 5;            // 128

    // ---- prologue: stage tiles 0,1 into bufs 0,1 (6 loads each) ----
#pragma unroll
    for (int g = 0; g < 4; ++g) STAGE_A(0, 0, g);
#pragma unroll
    for (int g = 0; g < 2; ++g) STAGE_B(0, 0, g);
#pragma unroll
    for (int g = 0; g < 4; ++g) STAGE_A(BUFSZ, 1, g);
#pragma unroll
    for (int g = 0; g < 2; ++g) STAGE_B(BUFSZ, 1, g);
    asm volatile("s_waitcnt vmcnt(6)" ::: "memory");   // tile 0 landed
    __builtin_amdgcn_s_barrier();

    int curO = 0;
    int stgO = 2 * BUFSZ;

#pragma unroll 1
    for (int T = 0; T < NT; ++T) {
        const bool st = (T + 2) < NT;
        f16x8 a[8], b[4];

        // ===== ph0: read a0-3 + all b; stage A(T+2) g0,g1; MFMA m0-3 =====
#pragma unroll
        for (int m = 0; m < 4; ++m) a[m] = LDA(curO, m);
#pragma unroll
        for (int n = 0; n < 4; ++n) b[n] = LDB(curO, n);
        if (st) { STAGE_A(stgO, T + 2, 0); STAGE_A(stgO, T + 2, 1); }
        __builtin_amdgcn_s_barrier();
        __builtin_amdgcn_s_setprio(1);
#pragma unroll
        for (int m = 0; m < 4; ++m)
#pragma unroll
            for (int n = 0; n < 4; ++n)
                acc[m][n] = __builtin_amdgcn_mfma_f32_16x16x32_f16(
                    a[m], b[n], acc[m][n], 0, 0, 0);
        __builtin_amdgcn_s_setprio(0);
        __builtin_amdgcn_s_barrier();

        // ===== ph1: read a4-7; stage A g2,g3 + B g0,g1; vmcnt(6); MFMA m4-7 =====
#pragma unroll
        for (int m = 0; m < 4; ++m) a[4 + m] = LDA(curO, 4 + m);
        if (st) {
            STAGE_A(stgO, T + 2, 2); STAGE_A(stgO, T + 2, 3);
            STAGE_B(stgO, T + 2, 0); STAGE_B(stgO, T + 2, 1);
        }
        if (T < NT - 2)       { asm volatile("s_waitcnt vmcnt(6)" ::: "memory"); }
        else if (T == NT - 2) { asm volatile("s_waitcnt vmcnt(0)" ::: "memory"); }
        __builtin_amdgcn_s_barrier();
        __builtin_amdgcn_s_setprio(1);
#pragma unroll
        for (int m = 0; m < 4; ++m)
#pragma unroll
            for (int n = 0; n < 4; ++n)
                acc[4 + m][n] = __builtin_amdgcn_mfma_f32_16x16x32_f16(
                    a[4 + m], b[n], acc[4 + m][n], 0, 0, 0);
        __builtin_amdgcn_s_setprio(0);
        __builtin_amdgcn_s_barrier();

        curO += BUFSZ; if (curO == NBUF * BUFSZ) curO = 0;
        stgO += BUFSZ; if (stgO == NBUF * BUFSZ) stgO = 0;
    }

    // ---- epilogue: + bias, f32 scatter stores (round-3-verified, no spill) ----
#pragma unroll
    for (int n = 0; n < 4; ++n) {
        const size_t gcol = n0 + wc * 64 + n * 16 + fr;
        const float bv = bias[gcol];
#pragma unroll
        for (int am = 0; am < 8; ++am) {
            const size_t grow = m0 + wr * 128 + am * 16 + fq * 4;
#pragma unroll
            for (int r = 0; r < 4; ++r)
                C[(grow + r) * N + gcol] = acc[am][n][r] + bv;
        }
    }
}

extern "C" void kernel_launch(void* const* d_in, const int* in_sizes, int n_in,
                              void* d_out, int out_size, void* d_ws, size_t ws_size,
                              hipStream_t stream) {
    const float* x      = (const float*)d_in[0];
    const int* packed   = (const int*)d_in[1];
    const float* wscale = (const float*)d_in[2];
    const float* wzero  = (const float*)d_in[3];
    const float* smooth = (const float*)d_in[4];
    const float* bias   = (const float*)d_in[5];
    float* out = (float*)d_out;

    const int K = in_sizes[4];             // 4096
    const int N = in_sizes[5];             // 11008
    const int M = in_sizes[0] / K;         // 8192
    const int MK = M * K;

    f16* xs = (f16*)d_ws;
    f16* Bt = (f16*)((char*)d_ws + (size_t)MK * sizeof(f16));

    smooth_kernel<<<(MK / 8 + 255) / 256, 256, 0, stream>>>(x, smooth, xs, MK, K);
    dequant_kernel<<<(N * (K >> 3) + 255) / 256, 256, 0, stream>>>(
        packed, wscale, wzero, Bt, N, K);

    const int grid_gemm = (M / BM) * (N / BN);
    gemm_kernel<<<grid_gemm, 256, 0, stream>>>(xs, Bt, bias, out, M, N, K);
}

// Round 7
// 826.621 us; speedup vs baseline: 1.3625x; 1.3357x over previous
//
#include <hip/hip_runtime.h>
#include <hip/hip_fp16.h>

typedef _Float16 f16;
typedef _Float16 f16x8 __attribute__((ext_vector_type(8)));
typedef float f32x4 __attribute__((ext_vector_type(4)));
typedef int int4v __attribute__((ext_vector_type(4)));
typedef unsigned char uchar;

#define BM 256
#define BN 256
#define BK 64                    // 64 int8 = 64B per row per tile
#define NBUF 4
#define BUFSZ 32768              // A 16KB + B 16KB

typedef const __attribute__((address_space(1))) unsigned int* gas_ptr;
typedef __attribute__((address_space(3))) unsigned int* las_ptr;

__device__ __forceinline__ void gload_lds16(const void* g, void* l) {
    __builtin_amdgcn_global_load_lds((gas_ptr)g, (las_ptr)l, 16, 0, 0);
}

// ---------------------------------------------------------------------------
// Pre-pass 1: per-row int8 quantization of xs = x/smooth.
// One wave per row (K=4096 held in 64 regs/lane). Outputs:
//   Aq[M][K] int8, sx[M] f32 (row scale), U[M][32] f16 (per-group sums of xs)
// ---------------------------------------------------------------------------
__global__ __launch_bounds__(256) void quantx_kernel(
    const float* __restrict__ x, const float* __restrict__ smooth,
    char* __restrict__ Aq, float* __restrict__ sx, f16* __restrict__ U,
    int M, int K)
{
    const int row = blockIdx.x * 4 + (threadIdx.x >> 6);
    const int lane = threadIdx.x & 63;
    if (row >= M) return;

    f32x4 xsv[16];
    float amax = 0.f;
#pragma unroll
    for (int j = 0; j < 16; ++j) {
        const int k = j * 256 + lane * 4;
        const f32x4 xv = *(const f32x4*)(x + (size_t)row * K + k);
        const f32x4 sv = *(const f32x4*)(smooth + k);
        f32x4 r;
#pragma unroll
        for (int e = 0; e < 4; ++e) {
            r[e] = xv[e] / sv[e];
            amax = fmaxf(amax, fabsf(r[e]));
        }
        xsv[j] = r;
    }
#pragma unroll
    for (int off = 1; off < 64; off <<= 1)
        amax = fmaxf(amax, __shfl_xor(amax, off));
    const float sxr = fmaxf(amax, 1e-20f) / 127.f;
    const float inv = 127.f / fmaxf(amax, 1e-20f);
    if (lane == 0) sx[row] = sxr;

    int* aq32 = (int*)(Aq + (size_t)row * K);
#pragma unroll
    for (int j = 0; j < 16; ++j) {
        unsigned int pk = 0;
        float s4 = 0.f;
#pragma unroll
        for (int e = 0; e < 4; ++e) {
            const float v = xsv[j][e];
            s4 += v;
            int qi = (int)__builtin_rintf(v * inv);
            qi = qi > 127 ? 127 : (qi < -127 ? -127 : qi);
            pk |= ((unsigned int)(qi & 255)) << (8 * e);
        }
        aq32[j * 64 + lane] = (int)pk;
        // group sums: this j covers groups 2j (lanes 0-31) and 2j+1 (32-63)
#pragma unroll
        for (int off = 1; off < 32; off <<= 1)
            s4 += __shfl_xor(s4, off);
        if ((lane & 31) == 0)
            U[(size_t)row * 32 + 2 * j + (lane >> 5)] = (f16)s4;
    }
}

// ---------------------------------------------------------------------------
// Pre-pass 2: unpack int32-per-byte nibbles -> Wq[N][K] int8 (q-8, exact).
// Thread handles 8 packed ints -> 16 int8.
// ---------------------------------------------------------------------------
__global__ __launch_bounds__(256) void repackw_kernel(
    const int* __restrict__ packed, char* __restrict__ Wq, int total8)
{
    const int i = blockIdx.x * 256 + threadIdx.x;
    if (i >= total8) return;
    const int4v p0 = *(const int4v*)(packed + i * 8);
    const int4v p1 = *(const int4v*)(packed + i * 8 + 4);
    int4v o;
#pragma unroll
    for (int w = 0; w < 4; ++w) {
        const int a = (w < 2) ? p0[2 * w] : p1[2 * (w - 2)];
        const int b = (w < 2) ? p0[2 * w + 1] : p1[2 * (w - 2) + 1];
        const int l0 = ((a & 15) - 8) & 255, h0 = (((a >> 4) & 15) - 8) & 255;
        const int l1 = ((b & 15) - 8) & 255, h1 = (((b >> 4) & 15) - 8) & 255;
        o[w] = l0 | (h0 << 8) | (l1 << 16) | (h1 << 24);
    }
    *(int4v*)(Wq + (size_t)i * 16) = o;
}

// ---------------------------------------------------------------------------
// Pre-pass 3: Vneg[N][32] f16 = -wscale[g][n] * wzero[g][n]
// ---------------------------------------------------------------------------
__global__ __launch_bounds__(256) void vneg_kernel(
    const float* __restrict__ wscale, const float* __restrict__ wzero,
    f16* __restrict__ Vneg, int N)
{
    const int i = blockIdx.x * 256 + threadIdx.x;
    if (i >= N * 32) return;
    const int n = i >> 5, g = i & 31;
    Vneg[i] = (f16)(-wscale[(size_t)g * N + n] * wzero[(size_t)g * N + n]);
}

// ---------------------------------------------------------------------------
// GEMM: accf[m][n] = sum_g s_g * (int-MFMA over group); epilogue applies
// sx (per row), rank-32 f16 MFMA zero-point correction, bias.
// Byte-level clone of the round-3 pipeline: 256x256 tile, BK=64(int8=64B/row),
// NBUF=4, stage T+3, counted vmcnt(8), 8 waves (2x4), XOR chunk swizzle
// (0 bank conflicts measured), supertile XCD swizzle.
// ---------------------------------------------------------------------------
__global__ __launch_bounds__(512, 2) void gemm_kernel(
    const char* __restrict__ Aq,       // [M][K] int8
    const char* __restrict__ Wq,       // [N][K] int8
    const float* __restrict__ wscale,  // [32][N] f32
    const float* __restrict__ sx,      // [M] f32
    const f16* __restrict__ U,         // [M][32] f16
    const f16* __restrict__ Vneg,      // [N][32] f16
    const float* __restrict__ bias,    // [N]
    float* __restrict__ C,             // [M][N] f32
    int M, int N, int K)
{
    __shared__ char lds[NBUF * BUFSZ];   // 128 KiB

    const int t = threadIdx.x;
    const int lane = t & 63;
    const int wid = t >> 6;
    const int wr = wid >> 2;          // 0..1
    const int wc = wid & 3;           // 0..3
    const int fr = lane & 15;
    const int fq = lane >> 4;

    const int nbm = M / BM;           // 32
    const int nbn = N / BN;           // 43
    const int nwg = nbm * nbn;        // 1376
    const int bid = (int)blockIdx.x;

    int bm, bn;
    if (nbm == 32 && nbn == 43) {
        const int x = bid & 7, s = bid >> 3;
        const int r = s >> 5, q = s & 31;
        const int pos = (r < 5) ? (r * 256 + x * 32 + q)
                                : (1280 + x * 12 + (s - 160));
        int st, w;
        if (pos < 1024)      { st = pos >> 8; w = pos & 255; }
        else if (pos < 1200) { st = 4;        w = pos - 1024; }
        else                 { st = 5;        w = pos - 1200; }
        if (st < 4) { bm = (st & 1) * 16 + (w >> 4); bn = (st >> 1) * 16 + (w & 15); }
        else        { bm = (st & 1) * 16 + (w / 11); bn = 32 + (w % 11); }
    } else {
        const int cpx = nwg >> 3;
        const int wg = (bid & 7) * cpx + (bid >> 3);
        bm = wg % nbm; bn = wg / nbm;
    }
    const size_t m0 = (size_t)bm * BM;
    const size_t n0 = (size_t)bn * BN;

    // ---- staging geometry (512 threads, 8KB per gload) ----
    const int scv = (t & 7) ^ ((t >> 3) & 7);
    const int rbase = 2 * (t >> 3) + (scv >> 2);   // 0..127
    const int kb = (scv & 3) * 16;                 // byte offset in 64B row
    const char* gAq = Aq + (m0 + rbase) * (size_t)K + kb;
    const char* gWq = Wq + (n0 + rbase) * (size_t)K + kb;

#define STAGE_A(sb, Tst) do { char* _d = lds + (sb) + t * 16; \
    gload_lds16(gAq + (size_t)(Tst) * BK, _d); \
    gload_lds16(gAq + (size_t)128 * K + (size_t)(Tst) * BK, _d + 8192); } while (0)
#define STAGE_B(sb, Tst) do { char* _d = lds + (sb) + 16384 + t * 16; \
    gload_lds16(gWq + (size_t)(Tst) * BK, _d); \
    gload_lds16(gWq + (size_t)128 * K + (size_t)(Tst) * BK, _d + 8192); } while (0)

    // ---- ds_read lane constants (r3-proven swizzle, byte-identical) ----
    const int aswz = ((((fr & 1) << 2) | fq) ^ ((fr >> 1) & 7)) << 4;
    const int aBase = wr * 8192 + ((fr >> 1) << 7) + aswz;
    const int bBase = 16384 + wc * 4096 + ((fr >> 1) << 7) + aswz;

#define LDA(db, m) (*(const int4v*)(lds + (db) + aBase + (m) * 1024))
#define LDB(db, n) (*(const int4v*)(lds + (db) + bBase + (n) * 1024))

    f32x4 accf[8][4];
#pragma unroll
    for (int m = 0; m < 8; ++m)
#pragma unroll
        for (int n = 0; n < 4; ++n)
            accf[m][n] = {0.f, 0.f, 0.f, 0.f};

    const int4v kz = {0, 0, 0, 0};
    const int NT = K >> 6;            // 64 tiles, group = T>>1

    // ---- prologue: stage tiles 0,1,2 ----
    STAGE_A(0, 0); STAGE_B(0, 0);
    STAGE_A(BUFSZ, 1); STAGE_B(BUFSZ, 1);
    STAGE_A(2 * BUFSZ, 2); STAGE_B(2 * BUFSZ, 2);
    asm volatile("s_waitcnt vmcnt(8)" ::: "memory");   // tile 0 landed
    __builtin_amdgcn_s_barrier();

#pragma unroll 1
    for (int T = 0; T < NT; ++T) {
        const int db = (T & 3) * BUFSZ;
        const int sb = ((T + 3) & 3) * BUFSZ;
        const bool st = (T + 3) < NT;
        const int g = T >> 1;

        float sgv[4];
#pragma unroll
        for (int n = 0; n < 4; ++n)
            sgv[n] = wscale[(size_t)g * N + n0 + wc * 64 + n * 16 + fr];

        // ===== ph0: read a0-3 + b0-3; stage A(T+3); MFMA+fixup m0-3 =====
        int4v av[4], bv4[4];
#pragma unroll
        for (int m = 0; m < 4; ++m) av[m] = LDA(db, m);
#pragma unroll
        for (int n = 0; n < 4; ++n) bv4[n] = LDB(db, n);
        if (st) STAGE_A(sb, T + 3);
        __builtin_amdgcn_s_barrier();
        __builtin_amdgcn_s_setprio(1);
#pragma unroll
        for (int m = 0; m < 4; ++m)
#pragma unroll
            for (int n = 0; n < 4; ++n) {
                const int4v tv = __builtin_amdgcn_mfma_i32_16x16x64_i8(
                    av[m], bv4[n], kz, 0, 0, 0);
#pragma unroll
                for (int e = 0; e < 4; ++e)
                    accf[m][n][e] += sgv[n] * (float)tv[e];
            }
        __builtin_amdgcn_s_setprio(0);
        __builtin_amdgcn_s_barrier();

        // ===== ph1: read a4-7; stage B(T+3); counted vmcnt; MFMA+fixup m4-7 =====
        int4v av2[4];
#pragma unroll
        for (int m = 0; m < 4; ++m) av2[m] = LDA(db, 4 + m);
        if (st) STAGE_B(sb, T + 3);
        if (T < NT - 3)       { asm volatile("s_waitcnt vmcnt(8)" ::: "memory"); }
        else if (T == NT - 3) { asm volatile("s_waitcnt vmcnt(4)" ::: "memory"); }
        else if (T == NT - 2) { asm volatile("s_waitcnt vmcnt(0)" ::: "memory"); }
        __builtin_amdgcn_s_barrier();
        __builtin_amdgcn_s_setprio(1);
#pragma unroll
        for (int m = 0; m < 4; ++m)
#pragma unroll
            for (int n = 0; n < 4; ++n) {
                const int4v tv = __builtin_amdgcn_mfma_i32_16x16x64_i8(
                    av2[m], bv4[n], kz, 0, 0, 0);
#pragma unroll
                for (int e = 0; e < 4; ++e)
                    accf[4 + m][n][e] += sgv[n] * (float)tv[e];
            }
        __builtin_amdgcn_s_setprio(0);
        __builtin_amdgcn_s_barrier();
    }

    // ---- epilogue 1: scale by per-row sx ----
#pragma unroll
    for (int m = 0; m < 8; ++m) {
        const f32x4 sxv = *(const f32x4*)(sx + m0 + wr * 128 + m * 16 + fq * 4);
#pragma unroll
        for (int n = 0; n < 4; ++n)
#pragma unroll
            for (int e = 0; e < 4; ++e)
                accf[m][n][e] *= sxv[e];
    }

    // ---- epilogue 2: rank-32 zero-point correction via f16 MFMA ----
    {
        f16x8 uf[8], vf[4];
#pragma unroll
        for (int m = 0; m < 8; ++m)
            uf[m] = *(const f16x8*)(U + (m0 + wr * 128 + m * 16 + fr) * 32 + fq * 8);
#pragma unroll
        for (int n = 0; n < 4; ++n)
            vf[n] = *(const f16x8*)(Vneg + (n0 + wc * 64 + n * 16 + fr) * 32 + fq * 8);
#pragma unroll
        for (int m = 0; m < 8; ++m)
#pragma unroll
            for (int n = 0; n < 4; ++n)
                accf[m][n] = __builtin_amdgcn_mfma_f32_16x16x32_f16(
                    uf[m], vf[n], accf[m][n], 0, 0, 0);
    }

    // ---- epilogue 3: + bias, f32 scatter stores (static indices) ----
#pragma unroll
    for (int n = 0; n < 4; ++n) {
        const size_t gcol = n0 + wc * 64 + n * 16 + fr;
        const float bv = bias[gcol];
#pragma unroll
        for (int am = 0; am < 8; ++am) {
            const size_t grow = m0 + wr * 128 + am * 16 + fq * 4;
#pragma unroll
            for (int r = 0; r < 4; ++r)
                C[(grow + r) * N + gcol] = accf[am][n][r] + bv;
        }
    }
}

extern "C" void kernel_launch(void* const* d_in, const int* in_sizes, int n_in,
                              void* d_out, int out_size, void* d_ws, size_t ws_size,
                              hipStream_t stream) {
    const float* x      = (const float*)d_in[0];
    const int* packed   = (const int*)d_in[1];
    const float* wscale = (const float*)d_in[2];
    const float* wzero  = (const float*)d_in[3];
    const float* smooth = (const float*)d_in[4];
    const float* bias   = (const float*)d_in[5];
    float* out = (float*)d_out;

    const int K = in_sizes[4];             // 4096
    const int N = in_sizes[5];             // 11008
    const int M = in_sizes[0] / K;         // 8192
    const size_t MK = (size_t)M * K;
    const size_t NK = (size_t)N * K;

    char* Aq  = (char*)d_ws;
    char* Wq  = Aq + MK;
    f16* U    = (f16*)(Wq + NK);
    f16* Vneg = U + (size_t)M * 32;
    float* sxp = (float*)(Vneg + (size_t)N * 32);

    quantx_kernel<<<(M + 3) / 4, 256, 0, stream>>>(x, smooth, Aq, sxp, U, M, K);
    const int total8 = (int)(NK / 16);
    repackw_kernel<<<(total8 + 255) / 256, 256, 0, stream>>>(packed, Wq, total8);
    vneg_kernel<<<(N * 32 + 255) / 256, 256, 0, stream>>>(wscale, wzero, Vneg, N);

    const int grid_gemm = (M / BM) * (N / BN);
    gemm_kernel<<<grid_gemm, 512, 0, stream>>>(
        Aq, Wq, wscale, sxp, U, Vneg, bias, out, M, N, K);
}